// Round 9
// baseline (575.497 us; speedup 1.0000x reference)
//
#include <hip/hip_runtime.h>
#include <stdint.h>
#include <stddef.h>

// Pipeline:
//  k_wt     : W [256][1024] -> Wt bf16 [1024][256] (transposed)
//  k_init   : denom=num=0, head=-1, pooled=0
//  k_link   : per-dst linked lists over original edges (atomicExch)
//  k_gemm   : BLK_M=128, 4 waves (wave=32 rows). A frags in registers (fp32->bf16
//             in-register). B strips double-buffered in LDS via global_load_lds
//             (WAVE-UNIFORM LDS base; pre-swizzled global source; XOR read).
//             a_s/a_d/s_row block-local plain stores, no atomics.
//  k_denom  : denom[dst,h] += p, num[dst,h] += p*s_row[src,h], pe[e,h] = p
//             (p=exp(lrelu(a_s[src]+a_d[dst])); self-loops at pe[E+node])
//  k_pool2  : pooled[h] = sum_dst num/denom  (64-block grid-stride reduce)
//  k_head   : a[h] = softmax(relu(pooled/(N*C)+biasmean)*cw+cb), hb[c]=sum_h a[h]bias
//  k_fuse   : per node (1 wave): h[n,c] = relu(sum_e sum_h avinv[h]*pe[e,h]*xw[src,h,c] + hb + x)
//             avinv hoisted; NO exp/div in the edge loop (was 68% VALUBusy)
//  k_out    : per edge (1 wave): out = log_softmax((h[s]*h[d]) @ linW + b)

typedef short bf16x8 __attribute__((ext_vector_type(8)));
typedef float f32x4 __attribute__((ext_vector_type(4)));
typedef unsigned short u16x8 __attribute__((ext_vector_type(8)));
typedef unsigned short u16x4 __attribute__((ext_vector_type(4)));

__device__ __forceinline__ unsigned short f2bf(float f) {
  unsigned u = __float_as_uint(f);
  u += 0x7FFFu + ((u >> 16) & 1u);
  return (unsigned short)(u >> 16);
}
__device__ __forceinline__ float bf2f(unsigned short s) {
  return __uint_as_float(((unsigned)s) << 16);
}
__device__ __forceinline__ float lrelu(float v) { return v >= 0.f ? v : 0.2f * v; }

__device__ __forceinline__ void gload16(const void* g, void* l) {
  __builtin_amdgcn_global_load_lds((const __attribute__((address_space(1))) void*)g,
                                   (__attribute__((address_space(3))) void*)l, 16, 0, 0);
}

// ---------------- weight transpose ----------------
__global__ __launch_bounds__(256) void k_wt(const float* __restrict__ W,
                                            unsigned short* __restrict__ wt) {
  int m = blockIdx.x * 256 + threadIdx.x;  // 0..1023
  for (int k = 0; k < 256; ++k) wt[(size_t)m * 256 + k] = f2bf(W[(size_t)k * 1024 + m]);
}

// ---------------- init + edge lists ----------------
__global__ __launch_bounds__(256) void k_init(float* __restrict__ denom, float* __restrict__ num,
                                              int* __restrict__ head, float* __restrict__ pooled, int n) {
  int i = blockIdx.x * 256 + threadIdx.x;
  if (i < n * 4) {
    denom[i] = 0.f;
    num[i] = 0.f;
  }
  if (i < n) head[i] = -1;
  if (i < 4) pooled[i] = 0.f;
}

__global__ __launch_bounds__(256) void k_link(const int* __restrict__ ei, int* __restrict__ head,
                                              int* __restrict__ nxt, int E) {
  int e = blockIdx.x * 256 + threadIdx.x;
  if (e >= E) return;
  int dst = ei[E + e];
  nxt[e] = atomicExch(&head[dst], e);
}

// ---------------- GEMM: xw = x @ W ----------------
// Block: 128 rows x 1024 cols, 4 waves, wave owns 32 rows (mi=0,1 x 16).
// A fragments in registers; B^T 64-col strips double-buffered in LDS (2x32KB),
// staged with async global_load_lds; LDS slot (r,c) holds global chunk
// (c ^ (r&15)); reads apply the same XOR -> 2-way conflicts (free).
// gload16 LDS base MUST be wave-uniform: HW places lane l at base + l*16.
__global__ __launch_bounds__(256, 2) void k_gemm(const float* __restrict__ X,          // [NR][256] fp32
                                                 const unsigned short* __restrict__ Bt,// [1024][256] bf16 (W^T)
                                                 const float* __restrict__ att_s_g,    // [1024]
                                                 const float* __restrict__ att_d_g,    // [1024]
                                                 unsigned short* __restrict__ C,       // [NR][1024] bf16
                                                 float* __restrict__ a_s, float* __restrict__ a_d,
                                                 float* __restrict__ s_row,
                                                 int NR) {
  __shared__ unsigned short Bs[2][64 * 256];  // 2 x 32 KB
  const int t = threadIdx.x;
  const int w = t >> 6, lane = t & 63;
  const int kc = lane >> 4, rl = lane & 15;
  const int row0 = blockIdx.x * 128 + w * 32;

  // ---- A fragments: aF[mi][kk] = X[row0+mi*16+rl][kk*32+kc*8 .. +8] as bf16 ----
  bf16x8 aF[2][8];
#pragma unroll
  for (int mi = 0; mi < 2; ++mi) {
    const int ar = min(row0 + mi * 16 + rl, NR - 1);
#pragma unroll
    for (int kk = 0; kk < 8; ++kk) {
      const float* xp = X + (size_t)ar * 256 + kk * 32 + kc * 8;
      float4 lo = *(const float4*)xp;
      float4 hi = *(const float4*)(xp + 4);
      bf16x8 v;
      v[0] = (short)f2bf(lo.x); v[1] = (short)f2bf(lo.y);
      v[2] = (short)f2bf(lo.z); v[3] = (short)f2bf(lo.w);
      v[4] = (short)f2bf(hi.x); v[5] = (short)f2bf(hi.y);
      v[6] = (short)f2bf(hi.z); v[7] = (short)f2bf(hi.w);
      aF[mi][kk] = v;
    }
  }

  // ---- stage strip 0 (uniform LDS base; per-lane global source) ----
#pragma unroll
  for (int i = 0; i < 8; ++i) {
    int idx = i * 256 + t;
    int r = idx >> 5, c = idx & 31;
    gload16(Bt + (size_t)r * 256 + ((c ^ (r & 15)) << 3),
            &Bs[0][(size_t)(i * 256 + w * 64) * 8]);
  }
  __syncthreads();

  float as_run[2][4], ad_run[2][4], sr_run[2][4];
#pragma unroll
  for (int mi = 0; mi < 2; ++mi)
#pragma unroll
    for (int j = 0; j < 4; ++j) { as_run[mi][j] = 0.f; ad_run[mi][j] = 0.f; sr_run[mi][j] = 0.f; }

#pragma unroll 1
  for (int hn = 0; hn < 16; ++hn) {
    const int cb0 = hn * 64;
    const int cur = hn & 1;
    // prefetch next strip (async; drained by the barrier at loop end)
    if (hn < 15) {
#pragma unroll
      for (int i = 0; i < 8; ++i) {
        int idx = i * 256 + t;
        int r = idx >> 5, c = idx & 31;
        gload16(Bt + (size_t)(cb0 + 64 + r) * 256 + ((c ^ (r & 15)) << 3),
                &Bs[cur ^ 1][(size_t)(i * 256 + w * 64) * 8]);
      }
    }

    f32x4 acc[2][4];
#pragma unroll
    for (int mi = 0; mi < 2; ++mi)
#pragma unroll
      for (int ni = 0; ni < 4; ++ni) acc[mi][ni] = (f32x4){0.f, 0.f, 0.f, 0.f};

#pragma unroll
    for (int kk = 0; kk < 8; ++kk) {
      bf16x8 bF[4];
#pragma unroll
      for (int ni = 0; ni < 4; ++ni)
        bF[ni] = *(const bf16x8*)&Bs[cur][(ni * 16 + rl) * 256 + (((kk * 4 + kc) ^ rl) << 3)];
#pragma unroll
      for (int mi = 0; mi < 2; ++mi)
#pragma unroll
        for (int ni = 0; ni < 4; ++ni)
          acc[mi][ni] = __builtin_amdgcn_mfma_f32_16x16x32_bf16(aF[mi][kk], bF[ni], acc[mi][ni], 0, 0, 0);
    }

    // ---- C store + attn partials (block-local, no atomics) ----
    float asv[4], adv[4];
#pragma unroll
    for (int ni = 0; ni < 4; ++ni) {
      asv[ni] = att_s_g[cb0 + ni * 16 + rl];
      adv[ni] = att_d_g[cb0 + ni * 16 + rl];
    }
#pragma unroll
    for (int mi = 0; mi < 2; ++mi)
#pragma unroll
      for (int j = 0; j < 4; ++j) {
        int row = row0 + mi * 16 + kc * 4 + j;
        bool ok = row < NR;
        float ps = 0.f, pd = 0.f, pr = 0.f;
#pragma unroll
        for (int ni = 0; ni < 4; ++ni) {
          float v = acc[mi][ni][j];
          ps += v * asv[ni];
          pd += v * adv[ni];
          pr += v;
          if (ok) C[(size_t)row * 1024 + cb0 + ni * 16 + rl] = f2bf(v);
        }
        as_run[mi][j] += ps; ad_run[mi][j] += pd; sr_run[mi][j] += pr;
      }
    // head boundary: reduce across the 16-lane column group, plain store
    if ((hn & 3) == 3) {
      const int h = hn >> 2;
#pragma unroll
      for (int mi = 0; mi < 2; ++mi)
#pragma unroll
        for (int j = 0; j < 4; ++j) {
          float ps = as_run[mi][j], pd = ad_run[mi][j], pr = sr_run[mi][j];
#pragma unroll
          for (int o = 1; o <= 8; o <<= 1) {
            ps += __shfl_xor(ps, o);
            pd += __shfl_xor(pd, o);
            pr += __shfl_xor(pr, o);
          }
          if (rl == 0) {
            int row = row0 + mi * 16 + kc * 4 + j;
            if (row < NR) {
              a_s[(size_t)row * 4 + h] = ps;
              a_d[(size_t)row * 4 + h] = pd;
              s_row[(size_t)row * 4 + h] = pr;
            }
          }
          as_run[mi][j] = 0.f; ad_run[mi][j] = 0.f; sr_run[mi][j] = 0.f;
        }
    }
    __syncthreads();
  }
}

// ---------------- per-edge denom + numerator + stored p (incl self-loops) ----------------
__global__ __launch_bounds__(256) void k_denom(const int* __restrict__ ei, const float* __restrict__ a_s,
                                               const float* __restrict__ a_d, const float* __restrict__ s_row,
                                               float* __restrict__ denom, float* __restrict__ num,
                                               float* __restrict__ pe,
                                               int E, int n) {
  int e = blockIdx.x * 256 + threadIdx.x;
  int tot = E + n;
  if (e >= tot) return;
  int src = e < E ? ei[e] : (e - E);
  int dst = e < E ? ei[E + e] : (e - E);
  float asv[4], adv[4], sv[4], pv[4];
  *(float4*)asv = *(const float4*)(a_s + (size_t)src * 4);
  *(float4*)adv = *(const float4*)(a_d + (size_t)dst * 4);
  *(float4*)sv = *(const float4*)(s_row + (size_t)src * 4);
#pragma unroll
  for (int h = 0; h < 4; ++h) {
    float p = expf(lrelu(asv[h] + adv[h]));
    pv[h] = p;
    atomicAdd(&denom[(size_t)dst * 4 + h], p);
    atomicAdd(&num[(size_t)dst * 4 + h], p * sv[h]);
  }
  *(float4*)(pe + (size_t)e * 4) = *(float4*)pv;
}

// ---------------- pooled[h] = sum_dst num/denom ----------------
__global__ __launch_bounds__(256) void k_pool2(const float* __restrict__ denom,
                                               const float* __restrict__ num,
                                               float* __restrict__ pooled, int n) {
  float ph[4] = {0.f, 0.f, 0.f, 0.f};
  for (int i = blockIdx.x * 256 + threadIdx.x; i < n; i += gridDim.x * 256) {
    float4 dv = *(const float4*)(denom + (size_t)i * 4);
    float4 nv = *(const float4*)(num + (size_t)i * 4);
    ph[0] += nv.x / (dv.x + 1e-16f);
    ph[1] += nv.y / (dv.y + 1e-16f);
    ph[2] += nv.z / (dv.z + 1e-16f);
    ph[3] += nv.w / (dv.w + 1e-16f);
  }
  int w = threadIdx.x >> 6, lane = threadIdx.x & 63;
#pragma unroll
  for (int h = 0; h < 4; ++h)
#pragma unroll
    for (int o = 32; o >= 1; o >>= 1) ph[h] += __shfl_xor(ph[h], o);
  __shared__ float red[4][4];
  if (lane == 0) {
#pragma unroll
    for (int h = 0; h < 4; ++h) red[w][h] = ph[h];
  }
  __syncthreads();
  if (threadIdx.x == 0) {
#pragma unroll
    for (int h = 0; h < 4; ++h)
      atomicAdd(&pooled[h], red[0][h] + red[1][h] + red[2][h] + red[3][h]);
  }
}

// ---------------- head gate + fused bias ----------------
__global__ __launch_bounds__(256) void k_head(const float* __restrict__ pooled,
                                              const float* __restrict__ gbias,
                                              const float* __restrict__ cw, const float* __restrict__ cb,
                                              float* __restrict__ a4, float* __restrict__ hb, int n) {
  __shared__ float red[4][4];
  __shared__ float aa[4];
  int t = threadIdx.x, w = t >> 6, lane = t & 63;
#pragma unroll
  for (int h = 0; h < 4; ++h) {
    float v = gbias[h * 256 + t];
#pragma unroll
    for (int o = 32; o >= 1; o >>= 1) v += __shfl_xor(v, o);
    if (lane == 0) red[h][w] = v;
  }
  __syncthreads();
  if (t == 0) {
    float q[4], mx = -1e30f;
    for (int h = 0; h < 4; ++h) {
      float bm = (red[h][0] + red[h][1] + red[h][2] + red[h][3]) * (1.f / 256.f);
      float pl = pooled[h] / ((float)n * 256.f) + bm;
      float c = pl * cw[0] + cb[0];
      c = fmaxf(c, 0.f);
      q[h] = c;
      mx = fmaxf(mx, c);
    }
    float sum = 0.f;
    for (int h = 0; h < 4; ++h) { q[h] = expf(q[h] - mx); sum += q[h]; }
    for (int h = 0; h < 4; ++h) { aa[h] = q[h] / sum; a4[h] = aa[h]; }
  }
  __syncthreads();
  float hbv = 0.f;
  for (int h = 0; h < 4; ++h) hbv += aa[h] * gbias[h * 256 + t];
  hb[t] = hbv;
}

// ---------------- per-node fused aggregation -> h (fp32) ----------------
// Inner loop has NO transcendentals: ws[h] = avinv[h] * pe[e][h].
__global__ __launch_bounds__(256) void k_fuse(const int* __restrict__ ei,
                                              const unsigned short* __restrict__ xwbf,
                                              const float* __restrict__ pe,
                                              const float* __restrict__ denom,
                                              const int* __restrict__ head, const int* __restrict__ nxt,
                                              const float* __restrict__ a4, const float* __restrict__ hb,
                                              const float* __restrict__ x, float* __restrict__ hbuf,
                                              int E, int n) {
  int node = blockIdx.x * 4 + (threadIdx.x >> 6);
  int lane = threadIdx.x & 63;
  if (node >= n) return;
  float dv[4], av[4], avinv[4];
  *(float4*)dv = *(const float4*)(denom + (size_t)node * 4);
  *(float4*)av = *(const float4*)a4;
#pragma unroll
  for (int h = 0; h < 4; ++h) avinv[h] = av[h] / (dv[h] + 1e-16f);
  float acc0 = 0.f, acc1 = 0.f, acc2 = 0.f, acc3 = 0.f;
  const int c0 = lane * 4;
  int j = node;           // self-loop first
  int e = E + node;       // pe slot of the self-loop (head/nxt entries are < E)
  const int eself = E + node;
  while (true) {
    float pv[4];
    *(float4*)pv = *(const float4*)(pe + (size_t)e * 4);
    float ws[4];
#pragma unroll
    for (int h = 0; h < 4; ++h) ws[h] = avinv[h] * pv[h];
    const unsigned short* rp = xwbf + (size_t)j * 1024;
#pragma unroll
    for (int h = 0; h < 4; ++h) {
      u16x4 q = *(const u16x4*)(rp + h * 256 + c0);
      acc0 += ws[h] * bf2f(q[0]);
      acc1 += ws[h] * bf2f(q[1]);
      acc2 += ws[h] * bf2f(q[2]);
      acc3 += ws[h] * bf2f(q[3]);
    }
    e = (e == eself) ? head[node] : nxt[e];
    if (e < 0) break;
    j = ei[e];
  }
  float4 xb = *(const float4*)(x + (size_t)node * 256 + c0);
  float4 hbv = *(const float4*)(hb + c0);
  float4 o;
  o.x = fmaxf(acc0 + hbv.x + xb.x, 0.f);
  o.y = fmaxf(acc1 + hbv.y + xb.y, 0.f);
  o.z = fmaxf(acc2 + hbv.z + xb.z, 0.f);
  o.w = fmaxf(acc3 + hbv.w + xb.w, 0.f);
  *(float4*)(hbuf + (size_t)node * 256 + c0) = o;
}

// ---------------- edge classifier + log_softmax ----------------
__global__ __launch_bounds__(256) void k_out(const int* __restrict__ ei,
                                             const float* __restrict__ hbuf,
                                             const float* __restrict__ linW, const float* __restrict__ linb,
                                             float* __restrict__ out, int E) {
  int gw = blockIdx.x * 4 + (threadIdx.x >> 6);
  int lane = threadIdx.x & 63;
  if (gw >= E) return;
  int src = ei[gw], dst = ei[E + gw];
  const int c0 = lane * 4;
  float4 hs = *(const float4*)(hbuf + (size_t)src * 256 + c0);
  float4 hd = *(const float4*)(hbuf + (size_t)dst * 256 + c0);
  float4 wa = *(const float4*)(linW + (size_t)c0 * 2);       // (c0,0),(c0,1),(c0+1,0),(c0+1,1)
  float4 wb = *(const float4*)(linW + (size_t)c0 * 2 + 4);   // (c0+2,0),(c0+2,1),(c0+3,0),(c0+3,1)
  float e0 = hs.x * hd.x, e1 = hs.y * hd.y, e2 = hs.z * hd.z, e3 = hs.w * hd.w;
  float u0 = e0 * wa.x + e1 * wa.z + e2 * wb.x + e3 * wb.z;
  float u1 = e0 * wa.y + e1 * wa.w + e2 * wb.y + e3 * wb.w;
#pragma unroll
  for (int o = 32; o >= 1; o >>= 1) {
    u0 += __shfl_xor(u0, o);
    u1 += __shfl_xor(u1, o);
  }
  if (lane == 0) {
    u0 += linb[0];
    u1 += linb[1];
    float mx = fmaxf(u0, u1);
    float lse = mx + logf(expf(u0 - mx) + expf(u1 - mx));
    float2 r;
    r.x = u0 - lse;
    r.y = u1 - lse;
    *(float2*)(out + (size_t)gw * 2) = r;
  }
}

// ---------------- launch ----------------
extern "C" void kernel_launch(void* const* d_in, const int* in_sizes, int n_in,
                              void* d_out, int out_size, void* d_ws, size_t ws_size,
                              hipStream_t stream) {
  const float* x = (const float*)d_in[0];
  const int* ei = (const int*)d_in[1];
  const float* W = (const float*)d_in[2];
  const float* att_s_g = (const float*)d_in[3];
  const float* att_d_g = (const float*)d_in[4];
  const float* gbias = (const float*)d_in[5];
  const float* cw = (const float*)d_in[6];
  const float* cb = (const float*)d_in[7];
  const float* linW = (const float*)d_in[8];
  const float* linb = (const float*)d_in[9];
  float* out = (float*)d_out;

  const int n = in_sizes[0] / 256;   // 100000
  const int E = in_sizes[1] / 2;     // 300000
  const int tot = E + n;

  char* p = (char*)d_ws;
  auto alloc = [&](size_t bytes) -> char* {
    char* r = p;
    p += (bytes + 255) & ~(size_t)255;
    return r;
  };
  unsigned short* xwbf = (unsigned short*)alloc((size_t)n * 1024 * 2);
  unsigned short* wtbf = (unsigned short*)alloc((size_t)1024 * 256 * 2);
  float* a_s = (float*)alloc((size_t)n * 4 * 4);
  float* a_d = (float*)alloc((size_t)n * 4 * 4);
  float* s_row = (float*)alloc((size_t)n * 4 * 4);
  float* denom = (float*)alloc((size_t)n * 4 * 4);
  float* num = (float*)alloc((size_t)n * 4 * 4);
  float* pe = (float*)alloc((size_t)tot * 4 * 4);
  int* head = (int*)alloc((size_t)n * 4);
  int* nxt = (int*)alloc((size_t)E * 4);
  float* pooled = (float*)alloc(256);
  float* a4 = (float*)alloc(256);
  float* hb = (float*)alloc(256 * 4);
  float* hbuf = (float*)alloc((size_t)n * 256 * 4);

  k_wt<<<dim3(4), dim3(256), 0, stream>>>(W, wtbf);
  k_init<<<dim3((n * 4 + 255) / 256), dim3(256), 0, stream>>>(denom, num, head, pooled, n);
  k_link<<<dim3((E + 255) / 256), dim3(256), 0, stream>>>(ei, head, nxt, E);
  k_gemm<<<dim3((n + 127) / 128), dim3(256), 0, stream>>>(x, wtbf, att_s_g, att_d_g, xwbf, a_s, a_d, s_row, n);
  k_denom<<<dim3((tot + 255) / 256), dim3(256), 0, stream>>>(ei, a_s, a_d, s_row, denom, num, pe, E, n);
  k_pool2<<<dim3(64), dim3(256), 0, stream>>>(denom, num, pooled, n);
  k_head<<<dim3(1), dim3(256), 0, stream>>>(pooled, gbias, cw, cb, a4, hb, n);
  k_fuse<<<dim3((n + 3) / 4), dim3(256), 0, stream>>>(ei, xwbf, pe, denom, head, nxt, a4, hb, x, hbuf, E, n);
  k_out<<<dim3((E + 3) / 4), dim3(256), 0, stream>>>(ei, hbuf, linW, linb, out, E);
}

// Round 12
// 537.467 us; speedup vs baseline: 1.0708x; 1.0708x over previous
//
#include <hip/hip_runtime.h>
#include <stdint.h>
#include <stddef.h>

// Pipeline:
//  k_wt     : W [256][1024] -> Wt fp16 [1024][256] (transposed; 1024 blocks)
//  k_init   : denom=num=0, head=-1, pooled=0
//  k_link   : per-dst linked lists over original edges (atomicExch)
//  k_gemm   : BLK_M=128, 4 waves (wave=32 rows). A frags in registers (fp32->FP16
//             in-register). B strips double-buffered in LDS via global_load_lds
//             (WAVE-UNIFORM LDS base; pre-swizzled global source; XOR read).
//             MFMA = f32_16x16x32_F16: fp16 inputs have 8x finer mantissa than
//             bf16 -> pipeline rel-error ~0.1% (bf16 inputs put the max-|ref|
//             element right at the 3.1%-relative threshold; rounds 8-11 jitter).
//             xw stored fp16. a_s/a_d/s_row block-local plain stores, no atomics.
//  k_denom  : denom[dst,h] += p, num[dst,h] += p*s_row[src,h], pe[e,h] = p
//  k_pool2  : pooled[h] = sum_dst num/denom  (64-block grid-stride reduce)
//  k_head   : a[h] = softmax(relu(pooled/(N*C)+biasmean)*cw+cb), hb[c]=sum_h a[h]bias
//  k_fuse   : per node (1 wave), single pass. ws[h] = avinv[h]*pe[e,h], no exp/div.
//  k_out    : per edge (1 wave): out = log_softmax((h[s]*h[d]) @ linW + b)

typedef _Float16 f16x8 __attribute__((ext_vector_type(8)));
typedef float f32x4 __attribute__((ext_vector_type(4)));
typedef unsigned short u16x8 __attribute__((ext_vector_type(8)));
typedef unsigned short u16x4 __attribute__((ext_vector_type(4)));

__device__ __forceinline__ unsigned short f2h(float f) {
  _Float16 h = (_Float16)f;  // RTNE v_cvt_f16_f32
  return __builtin_bit_cast(unsigned short, h);
}
__device__ __forceinline__ float h2f(unsigned short s) {
  return (float)__builtin_bit_cast(_Float16, s);
}
__device__ __forceinline__ float lrelu(float v) { return v >= 0.f ? v : 0.2f * v; }

__device__ __forceinline__ void gload16(const void* g, void* l) {
  __builtin_amdgcn_global_load_lds((const __attribute__((address_space(1))) void*)g,
                                   (__attribute__((address_space(3))) void*)l, 16, 0, 0);
}

// ---------------- weight transpose (parallel, coalesced writes; fp16) ----------------
__global__ __launch_bounds__(256) void k_wt(const float* __restrict__ W,
                                            unsigned short* __restrict__ wt) {
  int idx = blockIdx.x * 256 + threadIdx.x;  // 0..262143 ; idx = m*256 + k
  int m = idx >> 8, k = idx & 255;
  wt[idx] = f2h(W[(size_t)k * 1024 + m]);
}

// ---------------- init + edge lists ----------------
__global__ __launch_bounds__(256) void k_init(float* __restrict__ denom, float* __restrict__ num,
                                              int* __restrict__ head, float* __restrict__ pooled, int n) {
  int i = blockIdx.x * 256 + threadIdx.x;
  if (i < n * 4) {
    denom[i] = 0.f;
    num[i] = 0.f;
  }
  if (i < n) head[i] = -1;
  if (i < 4) pooled[i] = 0.f;
}

__global__ __launch_bounds__(256) void k_link(const int* __restrict__ ei, int* __restrict__ head,
                                              int* __restrict__ nxt, int E) {
  int e = blockIdx.x * 256 + threadIdx.x;
  if (e >= E) return;
  int dst = ei[E + e];
  nxt[e] = atomicExch(&head[dst], e);
}

// ---------------- GEMM: xw = x @ W (f16 MFMA) ----------------
// Block: 128 rows x 1024 cols, 4 waves, wave owns 32 rows (mi=0,1 x 16).
// A fragments in registers (fp16); B^T 64-col strips double-buffered in LDS
// (2x32KB), staged with async global_load_lds; LDS slot (r,c) holds global
// chunk (c ^ (r&15)); reads apply the same XOR -> 2-way conflicts (free).
// gload16 LDS base MUST be wave-uniform: HW places lane l at base + l*16.
__global__ __launch_bounds__(256, 2) void k_gemm(const float* __restrict__ X,          // [NR][256] fp32
                                                 const unsigned short* __restrict__ Bt,// [1024][256] fp16 (W^T)
                                                 const float* __restrict__ att_s_g,    // [1024]
                                                 const float* __restrict__ att_d_g,    // [1024]
                                                 unsigned short* __restrict__ C,       // [NR][1024] fp16
                                                 float* __restrict__ a_s, float* __restrict__ a_d,
                                                 float* __restrict__ s_row,
                                                 int NR) {
  __shared__ unsigned short Bs[2][64 * 256];  // 2 x 32 KB
  const int t = threadIdx.x;
  const int w = t >> 6, lane = t & 63;
  const int kc = lane >> 4, rl = lane & 15;
  const int row0 = blockIdx.x * 128 + w * 32;

  // ---- A fragments: aF[mi][kk] = X[row0+mi*16+rl][kk*32+kc*8 .. +8] as fp16 ----
  f16x8 aF[2][8];
#pragma unroll
  for (int mi = 0; mi < 2; ++mi) {
    const int ar = min(row0 + mi * 16 + rl, NR - 1);
#pragma unroll
    for (int kk = 0; kk < 8; ++kk) {
      const float* xp = X + (size_t)ar * 256 + kk * 32 + kc * 8;
      float4 lo = *(const float4*)xp;
      float4 hi = *(const float4*)(xp + 4);
      f16x8 v;
      v[0] = (_Float16)lo.x; v[1] = (_Float16)lo.y;
      v[2] = (_Float16)lo.z; v[3] = (_Float16)lo.w;
      v[4] = (_Float16)hi.x; v[5] = (_Float16)hi.y;
      v[6] = (_Float16)hi.z; v[7] = (_Float16)hi.w;
      aF[mi][kk] = v;
    }
  }

  // ---- stage strip 0 (uniform LDS base; per-lane global source) ----
#pragma unroll
  for (int i = 0; i < 8; ++i) {
    int idx = i * 256 + t;
    int r = idx >> 5, c = idx & 31;
    gload16(Bt + (size_t)r * 256 + ((c ^ (r & 15)) << 3),
            &Bs[0][(size_t)(i * 256 + w * 64) * 8]);
  }
  __syncthreads();

  float as_run[2][4], ad_run[2][4], sr_run[2][4];
#pragma unroll
  for (int mi = 0; mi < 2; ++mi)
#pragma unroll
    for (int j = 0; j < 4; ++j) { as_run[mi][j] = 0.f; ad_run[mi][j] = 0.f; sr_run[mi][j] = 0.f; }

#pragma unroll 1
  for (int hn = 0; hn < 16; ++hn) {
    const int cb0 = hn * 64;
    const int cur = hn & 1;
    // prefetch next strip (async; drained by the barrier at loop end)
    if (hn < 15) {
#pragma unroll
      for (int i = 0; i < 8; ++i) {
        int idx = i * 256 + t;
        int r = idx >> 5, c = idx & 31;
        gload16(Bt + (size_t)(cb0 + 64 + r) * 256 + ((c ^ (r & 15)) << 3),
                &Bs[cur ^ 1][(size_t)(i * 256 + w * 64) * 8]);
      }
    }

    f32x4 acc[2][4];
#pragma unroll
    for (int mi = 0; mi < 2; ++mi)
#pragma unroll
      for (int ni = 0; ni < 4; ++ni) acc[mi][ni] = (f32x4){0.f, 0.f, 0.f, 0.f};

#pragma unroll
    for (int kk = 0; kk < 8; ++kk) {
      f16x8 bF[4];
#pragma unroll
      for (int ni = 0; ni < 4; ++ni)
        bF[ni] = *(const f16x8*)&Bs[cur][(ni * 16 + rl) * 256 + (((kk * 4 + kc) ^ rl) << 3)];
#pragma unroll
      for (int mi = 0; mi < 2; ++mi)
#pragma unroll
        for (int ni = 0; ni < 4; ++ni)
          acc[mi][ni] = __builtin_amdgcn_mfma_f32_16x16x32_f16(aF[mi][kk], bF[ni], acc[mi][ni], 0, 0, 0);
    }

    // ---- C store (fp16) + attn partials (block-local, no atomics) ----
    float asv[4], adv[4];
#pragma unroll
    for (int ni = 0; ni < 4; ++ni) {
      asv[ni] = att_s_g[cb0 + ni * 16 + rl];
      adv[ni] = att_d_g[cb0 + ni * 16 + rl];
    }
#pragma unroll
    for (int mi = 0; mi < 2; ++mi)
#pragma unroll
      for (int j = 0; j < 4; ++j) {
        int row = row0 + mi * 16 + kc * 4 + j;
        bool ok = row < NR;
        float ps = 0.f, pd = 0.f, pr = 0.f;
#pragma unroll
        for (int ni = 0; ni < 4; ++ni) {
          float v = acc[mi][ni][j];
          ps += v * asv[ni];
          pd += v * adv[ni];
          pr += v;
          if (ok) C[(size_t)row * 1024 + cb0 + ni * 16 + rl] = f2h(v);
        }
        as_run[mi][j] += ps; ad_run[mi][j] += pd; sr_run[mi][j] += pr;
      }
    // head boundary: reduce across the 16-lane column group, plain store
    if ((hn & 3) == 3) {
      const int h = hn >> 2;
#pragma unroll
      for (int mi = 0; mi < 2; ++mi)
#pragma unroll
        for (int j = 0; j < 4; ++j) {
          float ps = as_run[mi][j], pd = ad_run[mi][j], pr = sr_run[mi][j];
#pragma unroll
          for (int o = 1; o <= 8; o <<= 1) {
            ps += __shfl_xor(ps, o);
            pd += __shfl_xor(pd, o);
            pr += __shfl_xor(pr, o);
          }
          if (rl == 0) {
            int row = row0 + mi * 16 + kc * 4 + j;
            if (row < NR) {
              a_s[(size_t)row * 4 + h] = ps;
              a_d[(size_t)row * 4 + h] = pd;
              s_row[(size_t)row * 4 + h] = pr;
            }
          }
          as_run[mi][j] = 0.f; ad_run[mi][j] = 0.f; sr_run[mi][j] = 0.f;
        }
    }
    __syncthreads();
  }
}

// ---------------- per-edge denom + numerator + stored p (incl self-loops) ----------------
__global__ __launch_bounds__(256) void k_denom(const int* __restrict__ ei, const float* __restrict__ a_s,
                                               const float* __restrict__ a_d, const float* __restrict__ s_row,
                                               float* __restrict__ denom, float* __restrict__ num,
                                               float* __restrict__ pe,
                                               int E, int n) {
  int e = blockIdx.x * 256 + threadIdx.x;
  int tot = E + n;
  if (e >= tot) return;
  int src = e < E ? ei[e] : (e - E);
  int dst = e < E ? ei[E + e] : (e - E);
  float asv[4], adv[4], sv[4], pv[4];
  *(float4*)asv = *(const float4*)(a_s + (size_t)src * 4);
  *(float4*)adv = *(const float4*)(a_d + (size_t)dst * 4);
  *(float4*)sv = *(const float4*)(s_row + (size_t)src * 4);
#pragma unroll
  for (int h = 0; h < 4; ++h) {
    float p = expf(lrelu(asv[h] + adv[h]));
    pv[h] = p;
    atomicAdd(&denom[(size_t)dst * 4 + h], p);
    atomicAdd(&num[(size_t)dst * 4 + h], p * sv[h]);
  }
  *(float4*)(pe + (size_t)e * 4) = *(float4*)pv;
}

// ---------------- pooled[h] = sum_dst num/denom ----------------
__global__ __launch_bounds__(256) void k_pool2(const float* __restrict__ denom,
                                               const float* __restrict__ num,
                                               float* __restrict__ pooled, int n) {
  float ph[4] = {0.f, 0.f, 0.f, 0.f};
  for (int i = blockIdx.x * 256 + threadIdx.x; i < n; i += gridDim.x * 256) {
    float4 dv = *(const float4*)(denom + (size_t)i * 4);
    float4 nv = *(const float4*)(num + (size_t)i * 4);
    ph[0] += nv.x / (dv.x + 1e-16f);
    ph[1] += nv.y / (dv.y + 1e-16f);
    ph[2] += nv.z / (dv.z + 1e-16f);
    ph[3] += nv.w / (dv.w + 1e-16f);
  }
  int w = threadIdx.x >> 6, lane = threadIdx.x & 63;
#pragma unroll
  for (int h = 0; h < 4; ++h)
#pragma unroll
    for (int o = 32; o >= 1; o >>= 1) ph[h] += __shfl_xor(ph[h], o);
  __shared__ float red[4][4];
  if (lane == 0) {
#pragma unroll
    for (int h = 0; h < 4; ++h) red[w][h] = ph[h];
  }
  __syncthreads();
  if (threadIdx.x == 0) {
#pragma unroll
    for (int h = 0; h < 4; ++h)
      atomicAdd(&pooled[h], red[0][h] + red[1][h] + red[2][h] + red[3][h]);
  }
}

// ---------------- head gate + fused bias ----------------
__global__ __launch_bounds__(256) void k_head(const float* __restrict__ pooled,
                                              const float* __restrict__ gbias,
                                              const float* __restrict__ cw, const float* __restrict__ cb,
                                              float* __restrict__ a4, float* __restrict__ hb, int n) {
  __shared__ float red[4][4];
  __shared__ float aa[4];
  int t = threadIdx.x, w = t >> 6, lane = t & 63;
#pragma unroll
  for (int h = 0; h < 4; ++h) {
    float v = gbias[h * 256 + t];
#pragma unroll
    for (int o = 32; o >= 1; o >>= 1) v += __shfl_xor(v, o);
    if (lane == 0) red[h][w] = v;
  }
  __syncthreads();
  if (t == 0) {
    float q[4], mx = -1e30f;
    for (int h = 0; h < 4; ++h) {
      float bm = (red[h][0] + red[h][1] + red[h][2] + red[h][3]) * (1.f / 256.f);
      float pl = pooled[h] / ((float)n * 256.f) + bm;
      float c = pl * cw[0] + cb[0];
      c = fmaxf(c, 0.f);
      q[h] = c;
      mx = fmaxf(mx, c);
    }
    float sum = 0.f;
    for (int h = 0; h < 4; ++h) { q[h] = expf(q[h] - mx); sum += q[h]; }
    for (int h = 0; h < 4; ++h) { aa[h] = q[h] / sum; a4[h] = aa[h]; }
  }
  __syncthreads();
  float hbv = 0.f;
  for (int h = 0; h < 4; ++h) hbv += aa[h] * gbias[h * 256 + t];
  hb[t] = hbv;
}

// ---------------- per-node fused aggregation -> h (fp32) ----------------
// Inner loop has NO transcendentals: ws[h] = avinv[h] * pe[e][h]; xw read fp16.
__global__ __launch_bounds__(256) void k_fuse(const int* __restrict__ ei,
                                              const unsigned short* __restrict__ xwh,
                                              const float* __restrict__ pe,
                                              const float* __restrict__ denom,
                                              const int* __restrict__ head, const int* __restrict__ nxt,
                                              const float* __restrict__ a4, const float* __restrict__ hb,
                                              const float* __restrict__ x, float* __restrict__ hbuf,
                                              int E, int n) {
  int node = blockIdx.x * 4 + (threadIdx.x >> 6);
  int lane = threadIdx.x & 63;
  if (node >= n) return;
  float dv[4], av[4], avinv[4];
  *(float4*)dv = *(const float4*)(denom + (size_t)node * 4);
  *(float4*)av = *(const float4*)a4;
#pragma unroll
  for (int h = 0; h < 4; ++h) avinv[h] = av[h] / (dv[h] + 1e-16f);
  float acc0 = 0.f, acc1 = 0.f, acc2 = 0.f, acc3 = 0.f;
  const int c0 = lane * 4;
  int j = node;           // self-loop first
  const int eself = E + node;
  int e = eself;
  while (true) {
    float pv[4];
    *(float4*)pv = *(const float4*)(pe + (size_t)e * 4);
    float ws[4];
#pragma unroll
    for (int h = 0; h < 4; ++h) ws[h] = avinv[h] * pv[h];
    const unsigned short* rp = xwh + (size_t)j * 1024;
#pragma unroll
    for (int h = 0; h < 4; ++h) {
      u16x4 q = *(const u16x4*)(rp + h * 256 + c0);
      acc0 += ws[h] * h2f(q[0]);
      acc1 += ws[h] * h2f(q[1]);
      acc2 += ws[h] * h2f(q[2]);
      acc3 += ws[h] * h2f(q[3]);
    }
    e = (e == eself) ? head[node] : nxt[e];
    if (e < 0) break;
    j = ei[e];
  }
  float4 xb = *(const float4*)(x + (size_t)node * 256 + c0);
  float4 hbv = *(const float4*)(hb + c0);
  float4 o;
  o.x = fmaxf(acc0 + hbv.x + xb.x, 0.f);
  o.y = fmaxf(acc1 + hbv.y + xb.y, 0.f);
  o.z = fmaxf(acc2 + hbv.z + xb.z, 0.f);
  o.w = fmaxf(acc3 + hbv.w + xb.w, 0.f);
  *(float4*)(hbuf + (size_t)node * 256 + c0) = o;
}

// ---------------- edge classifier + log_softmax ----------------
__global__ __launch_bounds__(256) void k_out(const int* __restrict__ ei,
                                             const float* __restrict__ hbuf,
                                             const float* __restrict__ linW, const float* __restrict__ linb,
                                             float* __restrict__ out, int E) {
  int gw = blockIdx.x * 4 + (threadIdx.x >> 6);
  int lane = threadIdx.x & 63;
  if (gw >= E) return;
  int src = ei[gw], dst = ei[E + gw];
  const int c0 = lane * 4;
  float4 hs = *(const float4*)(hbuf + (size_t)src * 256 + c0);
  float4 hd = *(const float4*)(hbuf + (size_t)dst * 256 + c0);
  float4 wa = *(const float4*)(linW + (size_t)c0 * 2);       // (c0,0),(c0,1),(c0+1,0),(c0+1,1)
  float4 wb = *(const float4*)(linW + (size_t)c0 * 2 + 4);   // (c0+2,0),(c0+2,1),(c0+3,0),(c0+3,1)
  float e0 = hs.x * hd.x, e1 = hs.y * hd.y, e2 = hs.z * hd.z, e3 = hs.w * hd.w;
  float u0 = e0 * wa.x + e1 * wa.z + e2 * wb.x + e3 * wb.z;
  float u1 = e0 * wa.y + e1 * wa.w + e2 * wb.y + e3 * wb.w;
#pragma unroll
  for (int o = 32; o >= 1; o >>= 1) {
    u0 += __shfl_xor(u0, o);
    u1 += __shfl_xor(u1, o);
  }
  if (lane == 0) {
    u0 += linb[0];
    u1 += linb[1];
    float mx = fmaxf(u0, u1);
    float lse = mx + logf(expf(u0 - mx) + expf(u1 - mx));
    float2 r;
    r.x = u0 - lse;
    r.y = u1 - lse;
    *(float2*)(out + (size_t)gw * 2) = r;
  }
}

// ---------------- launch ----------------
extern "C" void kernel_launch(void* const* d_in, const int* in_sizes, int n_in,
                              void* d_out, int out_size, void* d_ws, size_t ws_size,
                              hipStream_t stream) {
  const float* x = (const float*)d_in[0];
  const int* ei = (const int*)d_in[1];
  const float* W = (const float*)d_in[2];
  const float* att_s_g = (const float*)d_in[3];
  const float* att_d_g = (const float*)d_in[4];
  const float* gbias = (const float*)d_in[5];
  const float* cw = (const float*)d_in[6];
  const float* cb = (const float*)d_in[7];
  const float* linW = (const float*)d_in[8];
  const float* linb = (const float*)d_in[9];
  float* out = (float*)d_out;

  const int n = in_sizes[0] / 256;   // 100000
  const int E = in_sizes[1] / 2;     // 300000
  const int tot = E + n;

  char* p = (char*)d_ws;
  auto alloc = [&](size_t bytes) -> char* {
    char* r = p;
    p += (bytes + 255) & ~(size_t)255;
    return r;
  };
  unsigned short* xwh = (unsigned short*)alloc((size_t)n * 1024 * 2);
  unsigned short* wth = (unsigned short*)alloc((size_t)1024 * 256 * 2);
  float* a_s = (float*)alloc((size_t)n * 4 * 4);
  float* a_d = (float*)alloc((size_t)n * 4 * 4);
  float* s_row = (float*)alloc((size_t)n * 4 * 4);
  float* denom = (float*)alloc((size_t)n * 4 * 4);
  float* num = (float*)alloc((size_t)n * 4 * 4);
  float* pe = (float*)alloc((size_t)tot * 4 * 4);
  int* head = (int*)alloc((size_t)n * 4);
  int* nxt = (int*)alloc((size_t)E * 4);
  float* pooled = (float*)alloc(256);
  float* a4 = (float*)alloc(256);
  float* hb = (float*)alloc(256 * 4);
  float* hbuf = (float*)alloc((size_t)n * 256 * 4);

  k_wt<<<dim3(1024), dim3(256), 0, stream>>>(W, wth);
  k_init<<<dim3((n * 4 + 255) / 256), dim3(256), 0, stream>>>(denom, num, head, pooled, n);
  k_link<<<dim3((E + 255) / 256), dim3(256), 0, stream>>>(ei, head, nxt, E);
  k_gemm<<<dim3((n + 127) / 128), dim3(256), 0, stream>>>(x, wth, att_s_g, att_d_g, xwh, a_s, a_d, s_row, n);
  k_denom<<<dim3((tot + 255) / 256), dim3(256), 0, stream>>>(ei, a_s, a_d, s_row, denom, num, pe, E, n);
  k_pool2<<<dim3(64), dim3(256), 0, stream>>>(denom, num, pooled, n);
  k_head<<<dim3(1), dim3(256), 0, stream>>>(pooled, gbias, cw, cb, a4, hb, n);
  k_fuse<<<dim3((n + 3) / 4), dim3(256), 0, stream>>>(ei, xwh, pe, denom, head, nxt, a4, hb, x, hbuf, E, n);
  k_out<<<dim3((E + 3) / 4), dim3(256), 0, stream>>>(ei, hbuf, linW, linb, out, E);
}

// Round 13
// 511.846 us; speedup vs baseline: 1.1244x; 1.0501x over previous
//
#include <hip/hip_runtime.h>
#include <stdint.h>
#include <stddef.h>

// Pipeline:
//  k_wt     : W [256][1024] -> Wt fp16 [1024][256] (transposed; 1024 blocks)
//  k_init   : denom=num=0, head=-1, pooled=0
//  k_link   : per-dst linked lists over original edges (atomicExch)
//  k_gemm   : BLK_M=128, 4 waves (wave=32 rows). A frags in registers (fp32->FP16
//             in-register). B strips double-buffered in LDS via global_load_lds
//             (WAVE-UNIFORM LDS base; pre-swizzled global source; XOR read).
//             MFMA = f32_16x16x32_F16 (fp16 inputs: pipeline rel-err ~0.1%).
//             xw stored fp16. a_s/a_d/s_row block-local plain stores, no atomics.
//  k_denom  : denom[dst,h] += p, num[dst,h] += p*s_row[src,h], pe[e,h] = p
//  k_pool2  : pooled[h] = sum_dst num/denom  (64-block grid-stride reduce)
//  k_head   : a[h] = softmax(relu(pooled/(N*C)+biasmean)*cw+cb), hb[c]=sum_h a[h]bias
//  k_fuse   : per node (1 wave), single pass. ws[h] = avinv[h]*pe[e,h], no exp/div.
//             h stored FP16 (51MB table -> L3-resident for k_out's gather;
//             fp16 adds ~0.008 absmax vs the 0.06 that bf16 added in round 6).
//  k_out    : per edge (1 wave): out = log_softmax((h[s]*h[d]) @ linW + b); fp16 gather

typedef _Float16 f16x8 __attribute__((ext_vector_type(8)));
typedef float f32x4 __attribute__((ext_vector_type(4)));
typedef unsigned short u16x8 __attribute__((ext_vector_type(8)));
typedef unsigned short u16x4 __attribute__((ext_vector_type(4)));

__device__ __forceinline__ unsigned short f2h(float f) {
  _Float16 h = (_Float16)f;  // RTNE v_cvt_f16_f32
  return __builtin_bit_cast(unsigned short, h);
}
__device__ __forceinline__ float h2f(unsigned short s) {
  return (float)__builtin_bit_cast(_Float16, s);
}
__device__ __forceinline__ float lrelu(float v) { return v >= 0.f ? v : 0.2f * v; }

__device__ __forceinline__ void gload16(const void* g, void* l) {
  __builtin_amdgcn_global_load_lds((const __attribute__((address_space(1))) void*)g,
                                   (__attribute__((address_space(3))) void*)l, 16, 0, 0);
}

// ---------------- weight transpose (parallel, coalesced writes; fp16) ----------------
__global__ __launch_bounds__(256) void k_wt(const float* __restrict__ W,
                                            unsigned short* __restrict__ wt) {
  int idx = blockIdx.x * 256 + threadIdx.x;  // 0..262143 ; idx = m*256 + k
  int m = idx >> 8, k = idx & 255;
  wt[idx] = f2h(W[(size_t)k * 1024 + m]);
}

// ---------------- init + edge lists ----------------
__global__ __launch_bounds__(256) void k_init(float* __restrict__ denom, float* __restrict__ num,
                                              int* __restrict__ head, float* __restrict__ pooled, int n) {
  int i = blockIdx.x * 256 + threadIdx.x;
  if (i < n * 4) {
    denom[i] = 0.f;
    num[i] = 0.f;
  }
  if (i < n) head[i] = -1;
  if (i < 4) pooled[i] = 0.f;
}

__global__ __launch_bounds__(256) void k_link(const int* __restrict__ ei, int* __restrict__ head,
                                              int* __restrict__ nxt, int E) {
  int e = blockIdx.x * 256 + threadIdx.x;
  if (e >= E) return;
  int dst = ei[E + e];
  nxt[e] = atomicExch(&head[dst], e);
}

// ---------------- GEMM: xw = x @ W (f16 MFMA) ----------------
// Block: 128 rows x 1024 cols, 4 waves, wave owns 32 rows (mi=0,1 x 16).
// A fragments in registers (fp16); B^T 64-col strips double-buffered in LDS
// (2x32KB), staged with async global_load_lds; LDS slot (r,c) holds global
// chunk (c ^ (r&15)); reads apply the same XOR -> 2-way conflicts (free).
// gload16 LDS base MUST be wave-uniform: HW places lane l at base + l*16.
__global__ __launch_bounds__(256, 2) void k_gemm(const float* __restrict__ X,          // [NR][256] fp32
                                                 const unsigned short* __restrict__ Bt,// [1024][256] fp16 (W^T)
                                                 const float* __restrict__ att_s_g,    // [1024]
                                                 const float* __restrict__ att_d_g,    // [1024]
                                                 unsigned short* __restrict__ C,       // [NR][1024] fp16
                                                 float* __restrict__ a_s, float* __restrict__ a_d,
                                                 float* __restrict__ s_row,
                                                 int NR) {
  __shared__ unsigned short Bs[2][64 * 256];  // 2 x 32 KB
  const int t = threadIdx.x;
  const int w = t >> 6, lane = t & 63;
  const int kc = lane >> 4, rl = lane & 15;
  const int row0 = blockIdx.x * 128 + w * 32;

  // ---- A fragments: aF[mi][kk] = X[row0+mi*16+rl][kk*32+kc*8 .. +8] as fp16 ----
  f16x8 aF[2][8];
#pragma unroll
  for (int mi = 0; mi < 2; ++mi) {
    const int ar = min(row0 + mi * 16 + rl, NR - 1);
#pragma unroll
    for (int kk = 0; kk < 8; ++kk) {
      const float* xp = X + (size_t)ar * 256 + kk * 32 + kc * 8;
      float4 lo = *(const float4*)xp;
      float4 hi = *(const float4*)(xp + 4);
      f16x8 v;
      v[0] = (_Float16)lo.x; v[1] = (_Float16)lo.y;
      v[2] = (_Float16)lo.z; v[3] = (_Float16)lo.w;
      v[4] = (_Float16)hi.x; v[5] = (_Float16)hi.y;
      v[6] = (_Float16)hi.z; v[7] = (_Float16)hi.w;
      aF[mi][kk] = v;
    }
  }

  // ---- stage strip 0 (uniform LDS base; per-lane global source) ----
#pragma unroll
  for (int i = 0; i < 8; ++i) {
    int idx = i * 256 + t;
    int r = idx >> 5, c = idx & 31;
    gload16(Bt + (size_t)r * 256 + ((c ^ (r & 15)) << 3),
            &Bs[0][(size_t)(i * 256 + w * 64) * 8]);
  }
  __syncthreads();

  float as_run[2][4], ad_run[2][4], sr_run[2][4];
#pragma unroll
  for (int mi = 0; mi < 2; ++mi)
#pragma unroll
    for (int j = 0; j < 4; ++j) { as_run[mi][j] = 0.f; ad_run[mi][j] = 0.f; sr_run[mi][j] = 0.f; }

#pragma unroll 1
  for (int hn = 0; hn < 16; ++hn) {
    const int cb0 = hn * 64;
    const int cur = hn & 1;
    // prefetch next strip (async; drained by the barrier at loop end)
    if (hn < 15) {
#pragma unroll
      for (int i = 0; i < 8; ++i) {
        int idx = i * 256 + t;
        int r = idx >> 5, c = idx & 31;
        gload16(Bt + (size_t)(cb0 + 64 + r) * 256 + ((c ^ (r & 15)) << 3),
                &Bs[cur ^ 1][(size_t)(i * 256 + w * 64) * 8]);
      }
    }

    f32x4 acc[2][4];
#pragma unroll
    for (int mi = 0; mi < 2; ++mi)
#pragma unroll
      for (int ni = 0; ni < 4; ++ni) acc[mi][ni] = (f32x4){0.f, 0.f, 0.f, 0.f};

#pragma unroll
    for (int kk = 0; kk < 8; ++kk) {
      f16x8 bF[4];
#pragma unroll
      for (int ni = 0; ni < 4; ++ni)
        bF[ni] = *(const f16x8*)&Bs[cur][(ni * 16 + rl) * 256 + (((kk * 4 + kc) ^ rl) << 3)];
#pragma unroll
      for (int mi = 0; mi < 2; ++mi)
#pragma unroll
        for (int ni = 0; ni < 4; ++ni)
          acc[mi][ni] = __builtin_amdgcn_mfma_f32_16x16x32_f16(aF[mi][kk], bF[ni], acc[mi][ni], 0, 0, 0);
    }

    // ---- C store (fp16) + attn partials (block-local, no atomics) ----
    float asv[4], adv[4];
#pragma unroll
    for (int ni = 0; ni < 4; ++ni) {
      asv[ni] = att_s_g[cb0 + ni * 16 + rl];
      adv[ni] = att_d_g[cb0 + ni * 16 + rl];
    }
#pragma unroll
    for (int mi = 0; mi < 2; ++mi)
#pragma unroll
      for (int j = 0; j < 4; ++j) {
        int row = row0 + mi * 16 + kc * 4 + j;
        bool ok = row < NR;
        float ps = 0.f, pd = 0.f, pr = 0.f;
#pragma unroll
        for (int ni = 0; ni < 4; ++ni) {
          float v = acc[mi][ni][j];
          ps += v * asv[ni];
          pd += v * adv[ni];
          pr += v;
          if (ok) C[(size_t)row * 1024 + cb0 + ni * 16 + rl] = f2h(v);
        }
        as_run[mi][j] += ps; ad_run[mi][j] += pd; sr_run[mi][j] += pr;
      }
    // head boundary: reduce across the 16-lane column group, plain store
    if ((hn & 3) == 3) {
      const int h = hn >> 2;
#pragma unroll
      for (int mi = 0; mi < 2; ++mi)
#pragma unroll
        for (int j = 0; j < 4; ++j) {
          float ps = as_run[mi][j], pd = ad_run[mi][j], pr = sr_run[mi][j];
#pragma unroll
          for (int o = 1; o <= 8; o <<= 1) {
            ps += __shfl_xor(ps, o);
            pd += __shfl_xor(pd, o);
            pr += __shfl_xor(pr, o);
          }
          if (rl == 0) {
            int row = row0 + mi * 16 + kc * 4 + j;
            if (row < NR) {
              a_s[(size_t)row * 4 + h] = ps;
              a_d[(size_t)row * 4 + h] = pd;
              s_row[(size_t)row * 4 + h] = pr;
            }
          }
          as_run[mi][j] = 0.f; ad_run[mi][j] = 0.f; sr_run[mi][j] = 0.f;
        }
    }
    __syncthreads();
  }
}

// ---------------- per-edge denom + numerator + stored p (incl self-loops) ----------------
__global__ __launch_bounds__(256) void k_denom(const int* __restrict__ ei, const float* __restrict__ a_s,
                                               const float* __restrict__ a_d, const float* __restrict__ s_row,
                                               float* __restrict__ denom, float* __restrict__ num,
                                               float* __restrict__ pe,
                                               int E, int n) {
  int e = blockIdx.x * 256 + threadIdx.x;
  int tot = E + n;
  if (e >= tot) return;
  int src = e < E ? ei[e] : (e - E);
  int dst = e < E ? ei[E + e] : (e - E);
  float asv[4], adv[4], sv[4], pv[4];
  *(float4*)asv = *(const float4*)(a_s + (size_t)src * 4);
  *(float4*)adv = *(const float4*)(a_d + (size_t)dst * 4);
  *(float4*)sv = *(const float4*)(s_row + (size_t)src * 4);
#pragma unroll
  for (int h = 0; h < 4; ++h) {
    float p = expf(lrelu(asv[h] + adv[h]));
    pv[h] = p;
    atomicAdd(&denom[(size_t)dst * 4 + h], p);
    atomicAdd(&num[(size_t)dst * 4 + h], p * sv[h]);
  }
  *(float4*)(pe + (size_t)e * 4) = *(float4*)pv;
}

// ---------------- pooled[h] = sum_dst num/denom ----------------
__global__ __launch_bounds__(256) void k_pool2(const float* __restrict__ denom,
                                               const float* __restrict__ num,
                                               float* __restrict__ pooled, int n) {
  float ph[4] = {0.f, 0.f, 0.f, 0.f};
  for (int i = blockIdx.x * 256 + threadIdx.x; i < n; i += gridDim.x * 256) {
    float4 dv = *(const float4*)(denom + (size_t)i * 4);
    float4 nv = *(const float4*)(num + (size_t)i * 4);
    ph[0] += nv.x / (dv.x + 1e-16f);
    ph[1] += nv.y / (dv.y + 1e-16f);
    ph[2] += nv.z / (dv.z + 1e-16f);
    ph[3] += nv.w / (dv.w + 1e-16f);
  }
  int w = threadIdx.x >> 6, lane = threadIdx.x & 63;
#pragma unroll
  for (int h = 0; h < 4; ++h)
#pragma unroll
    for (int o = 32; o >= 1; o >>= 1) ph[h] += __shfl_xor(ph[h], o);
  __shared__ float red[4][4];
  if (lane == 0) {
#pragma unroll
    for (int h = 0; h < 4; ++h) red[w][h] = ph[h];
  }
  __syncthreads();
  if (threadIdx.x == 0) {
#pragma unroll
    for (int h = 0; h < 4; ++h)
      atomicAdd(&pooled[h], red[0][h] + red[1][h] + red[2][h] + red[3][h]);
  }
}

// ---------------- head gate + fused bias ----------------
__global__ __launch_bounds__(256) void k_head(const float* __restrict__ pooled,
                                              const float* __restrict__ gbias,
                                              const float* __restrict__ cw, const float* __restrict__ cb,
                                              float* __restrict__ a4, float* __restrict__ hb, int n) {
  __shared__ float red[4][4];
  __shared__ float aa[4];
  int t = threadIdx.x, w = t >> 6, lane = t & 63;
#pragma unroll
  for (int h = 0; h < 4; ++h) {
    float v = gbias[h * 256 + t];
#pragma unroll
    for (int o = 32; o >= 1; o >>= 1) v += __shfl_xor(v, o);
    if (lane == 0) red[h][w] = v;
  }
  __syncthreads();
  if (t == 0) {
    float q[4], mx = -1e30f;
    for (int h = 0; h < 4; ++h) {
      float bm = (red[h][0] + red[h][1] + red[h][2] + red[h][3]) * (1.f / 256.f);
      float pl = pooled[h] / ((float)n * 256.f) + bm;
      float c = pl * cw[0] + cb[0];
      c = fmaxf(c, 0.f);
      q[h] = c;
      mx = fmaxf(mx, c);
    }
    float sum = 0.f;
    for (int h = 0; h < 4; ++h) { q[h] = expf(q[h] - mx); sum += q[h]; }
    for (int h = 0; h < 4; ++h) { aa[h] = q[h] / sum; a4[h] = aa[h]; }
  }
  __syncthreads();
  float hbv = 0.f;
  for (int h = 0; h < 4; ++h) hbv += aa[h] * gbias[h * 256 + t];
  hb[t] = hbv;
}

// ---------------- per-node fused aggregation -> h (fp16 out) ----------------
// Inner loop has NO transcendentals: ws[h] = avinv[h] * pe[e][h]; xw read fp16.
__global__ __launch_bounds__(256) void k_fuse(const int* __restrict__ ei,
                                              const unsigned short* __restrict__ xwh,
                                              const float* __restrict__ pe,
                                              const float* __restrict__ denom,
                                              const int* __restrict__ head, const int* __restrict__ nxt,
                                              const float* __restrict__ a4, const float* __restrict__ hb,
                                              const float* __restrict__ x, unsigned short* __restrict__ hbuf,
                                              int E, int n) {
  int node = blockIdx.x * 4 + (threadIdx.x >> 6);
  int lane = threadIdx.x & 63;
  if (node >= n) return;
  float dv[4], av[4], avinv[4];
  *(float4*)dv = *(const float4*)(denom + (size_t)node * 4);
  *(float4*)av = *(const float4*)a4;
#pragma unroll
  for (int h = 0; h < 4; ++h) avinv[h] = av[h] / (dv[h] + 1e-16f);
  float acc0 = 0.f, acc1 = 0.f, acc2 = 0.f, acc3 = 0.f;
  const int c0 = lane * 4;
  int j = node;           // self-loop first
  const int eself = E + node;
  int e = eself;
  while (true) {
    float pv[4];
    *(float4*)pv = *(const float4*)(pe + (size_t)e * 4);
    float ws[4];
#pragma unroll
    for (int h = 0; h < 4; ++h) ws[h] = avinv[h] * pv[h];
    const unsigned short* rp = xwh + (size_t)j * 1024;
#pragma unroll
    for (int h = 0; h < 4; ++h) {
      u16x4 q = *(const u16x4*)(rp + h * 256 + c0);
      acc0 += ws[h] * h2f(q[0]);
      acc1 += ws[h] * h2f(q[1]);
      acc2 += ws[h] * h2f(q[2]);
      acc3 += ws[h] * h2f(q[3]);
    }
    e = (e == eself) ? head[node] : nxt[e];
    if (e < 0) break;
    j = ei[e];
  }
  float4 xb = *(const float4*)(x + (size_t)node * 256 + c0);
  float4 hbv = *(const float4*)(hb + c0);
  u16x4 o;
  o[0] = f2h(fmaxf(acc0 + hbv.x + xb.x, 0.f));
  o[1] = f2h(fmaxf(acc1 + hbv.y + xb.y, 0.f));
  o[2] = f2h(fmaxf(acc2 + hbv.z + xb.z, 0.f));
  o[3] = f2h(fmaxf(acc3 + hbv.w + xb.w, 0.f));
  *(u16x4*)(hbuf + (size_t)node * 256 + c0) = o;
}

// ---------------- edge classifier + log_softmax (fp16 gather) ----------------
__global__ __launch_bounds__(256) void k_out(const int* __restrict__ ei,
                                             const unsigned short* __restrict__ hbuf,
                                             const float* __restrict__ linW, const float* __restrict__ linb,
                                             float* __restrict__ out, int E) {
  int gw = blockIdx.x * 4 + (threadIdx.x >> 6);
  int lane = threadIdx.x & 63;
  if (gw >= E) return;
  int src = ei[gw], dst = ei[E + gw];
  const int c0 = lane * 4;
  u16x4 qs = *(const u16x4*)(hbuf + (size_t)src * 256 + c0);
  u16x4 qd = *(const u16x4*)(hbuf + (size_t)dst * 256 + c0);
  float4 wa = *(const float4*)(linW + (size_t)c0 * 2);       // (c0,0),(c0,1),(c0+1,0),(c0+1,1)
  float4 wb = *(const float4*)(linW + (size_t)c0 * 2 + 4);   // (c0+2,0),(c0+2,1),(c0+3,0),(c0+3,1)
  float e0 = h2f(qs[0]) * h2f(qd[0]);
  float e1 = h2f(qs[1]) * h2f(qd[1]);
  float e2 = h2f(qs[2]) * h2f(qd[2]);
  float e3 = h2f(qs[3]) * h2f(qd[3]);
  float u0 = e0 * wa.x + e1 * wa.z + e2 * wb.x + e3 * wb.z;
  float u1 = e0 * wa.y + e1 * wa.w + e2 * wb.y + e3 * wb.w;
#pragma unroll
  for (int o = 32; o >= 1; o >>= 1) {
    u0 += __shfl_xor(u0, o);
    u1 += __shfl_xor(u1, o);
  }
  if (lane == 0) {
    u0 += linb[0];
    u1 += linb[1];
    float mx = fmaxf(u0, u1);
    float lse = mx + logf(expf(u0 - mx) + expf(u1 - mx));
    float2 r;
    r.x = u0 - lse;
    r.y = u1 - lse;
    *(float2*)(out + (size_t)gw * 2) = r;
  }
}

// ---------------- launch ----------------
extern "C" void kernel_launch(void* const* d_in, const int* in_sizes, int n_in,
                              void* d_out, int out_size, void* d_ws, size_t ws_size,
                              hipStream_t stream) {
  const float* x = (const float*)d_in[0];
  const int* ei = (const int*)d_in[1];
  const float* W = (const float*)d_in[2];
  const float* att_s_g = (const float*)d_in[3];
  const float* att_d_g = (const float*)d_in[4];
  const float* gbias = (const float*)d_in[5];
  const float* cw = (const float*)d_in[6];
  const float* cb = (const float*)d_in[7];
  const float* linW = (const float*)d_in[8];
  const float* linb = (const float*)d_in[9];
  float* out = (float*)d_out;

  const int n = in_sizes[0] / 256;   // 100000
  const int E = in_sizes[1] / 2;     // 300000
  const int tot = E + n;

  char* p = (char*)d_ws;
  auto alloc = [&](size_t bytes) -> char* {
    char* r = p;
    p += (bytes + 255) & ~(size_t)255;
    return r;
  };
  unsigned short* xwh = (unsigned short*)alloc((size_t)n * 1024 * 2);
  unsigned short* wth = (unsigned short*)alloc((size_t)1024 * 256 * 2);
  float* a_s = (float*)alloc((size_t)n * 4 * 4);
  float* a_d = (float*)alloc((size_t)n * 4 * 4);
  float* s_row = (float*)alloc((size_t)n * 4 * 4);
  float* denom = (float*)alloc((size_t)n * 4 * 4);
  float* num = (float*)alloc((size_t)n * 4 * 4);
  float* pe = (float*)alloc((size_t)tot * 4 * 4);
  int* head = (int*)alloc((size_t)n * 4);
  int* nxt = (int*)alloc((size_t)E * 4);
  float* pooled = (float*)alloc(256);
  float* a4 = (float*)alloc(256);
  float* hb = (float*)alloc(256 * 4);
  unsigned short* hbuf = (unsigned short*)alloc((size_t)n * 256 * 2);

  k_wt<<<dim3(1024), dim3(256), 0, stream>>>(W, wth);
  k_init<<<dim3((n * 4 + 255) / 256), dim3(256), 0, stream>>>(denom, num, head, pooled, n);
  k_link<<<dim3((E + 255) / 256), dim3(256), 0, stream>>>(ei, head, nxt, E);
  k_gemm<<<dim3((n + 127) / 128), dim3(256), 0, stream>>>(x, wth, att_s_g, att_d_g, xwh, a_s, a_d, s_row, n);
  k_denom<<<dim3((tot + 255) / 256), dim3(256), 0, stream>>>(ei, a_s, a_d, s_row, denom, num, pe, E, n);
  k_pool2<<<dim3(64), dim3(256), 0, stream>>>(denom, num, pooled, n);
  k_head<<<dim3(1), dim3(256), 0, stream>>>(pooled, gbias, cw, cb, a4, hb, n);
  k_fuse<<<dim3((n + 3) / 4), dim3(256), 0, stream>>>(ei, xwh, pe, denom, head, nxt, a4, hb, x, hbuf, E, n);
  k_out<<<dim3((E + 3) / 4), dim3(256), 0, stream>>>(ei, hbuf, linW, linb, out, E);
}